// Round 5
// baseline (634.263 us; speedup 1.0000x reference)
//
#include <hip/hip_runtime.h>

typedef unsigned short u16;
typedef unsigned int   u32;
typedef __attribute__((ext_vector_type(8))) short short8;   // 8 bf16 (4 VGPRs)
typedef __attribute__((ext_vector_type(4))) float f32x4;

#define D_DIM 1024
#define A_DIM 1024
#define T_DIM 2048
#define B_DIM 32
#define M_TOT (B_DIM * T_DIM)   // 65536
#define NSLICE 16

// ---- ws layout (bytes) ----
// [0)        scores/a : 65536 f32  (256 KB)
// [262144)   wsa      : 32768 f32  (128 KB)
// [393216)   cpart    : NSLICE*32768 f32 (2 MB)
// [2490368)  Ut bf16  : 1024*1024 u16 (2 MB)
#define WS_NEEDED 4587520

__device__ inline u32 cvt_pk_bf16(float lo, float hi) {
    u32 r;
    asm volatile("v_cvt_pk_bf16_f32 %0, %1, %2" : "=v"(r) : "v"(lo), "v"(hi));
    return r;
}

__device__ inline float fast_tanh(float x) {
    // tanh(x) = 1 - 2/(exp(2x)+1); exp(2x) = exp2(x * 2*log2(e))
    float e = __builtin_amdgcn_exp2f(x * 2.8853900817779268f);
    float r = __builtin_amdgcn_rcpf(e + 1.0f);
    return fmaf(-2.0f, r, 1.0f);
}

// ---------------- K0a: Ut[a][d] = bf16(U[d][a]) ----------------
__global__ __launch_bounds__(256) void k_transpose_U(const float* __restrict__ U,
                                                     u16* __restrict__ Ut) {
    __shared__ float tile[64][65];
    const int n0 = blockIdx.x * 64;   // a
    const int k0 = blockIdx.y * 64;   // d
    const int t = threadIdx.x;
    const int kk = t >> 4;            // 0..15
    const int nn = (t & 15) * 4;
#pragma unroll
    for (int p = 0; p < 4; ++p) {
        const float4 v = *(const float4*)&U[(size_t)(k0 + kk + p * 16) * A_DIM + n0 + nn];
        tile[kk + p * 16][nn + 0] = v.x;
        tile[kk + p * 16][nn + 1] = v.y;
        tile[kk + p * 16][nn + 2] = v.z;
        tile[kk + p * 16][nn + 3] = v.w;
    }
    __syncthreads();
    const int nn2 = t >> 2;           // 0..63
    const int kc = (t & 3) * 16;      // 0,16,32,48
    u32 u[8];
#pragma unroll
    for (int j = 0; j < 8; ++j)
        u[j] = cvt_pk_bf16(tile[kc + 2 * j][nn2], tile[kc + 2 * j + 1][nn2]);
    int4 w0 = {(int)u[0], (int)u[1], (int)u[2], (int)u[3]};
    int4 w1 = {(int)u[4], (int)u[5], (int)u[6], (int)u[7]};
    u16* dst = Ut + (size_t)(n0 + nn2) * D_DIM + k0 + kc;
    *(int4*)(dst) = w0;
    *(int4*)(dst + 8) = w1;
}

// ---------------- K0b: wsa[b][a] = sum_d s[b][d] * W[d][a] ----------------
__global__ __launch_bounds__(256) void k_ws(const float* __restrict__ s,
                                            const float* __restrict__ W,
                                            float* __restrict__ wsa) {
    const int a = blockIdx.x * 256 + threadIdx.x;
    const int b = blockIdx.y;
    const float* sb = s + (size_t)b * D_DIM;
    float acc = 0.f;
#pragma unroll 8
    for (int d = 0; d < D_DIM; ++d)
        acc = fmaf(sb[d], W[(size_t)d * A_DIM + a], acc);
    wsa[(size_t)b * A_DIM + a] = acc;
}

// ---------------- K1: fused scores GEMM ----------------
// scores[m] = sum_a v[a] * tanh( wsa[b][a] + sum_d h[m][d]*U[d][a] )
#define BM 128
#define BN 512
#define BK 64
#define NT (A_DIM / BN)      // 2
#define KSTEPS (D_DIM / BK)  // 16

__global__ __launch_bounds__(512) void k_scores(const float* __restrict__ h,
                                                const u16* __restrict__ Ut,
                                                const float* __restrict__ wsa,
                                                const float* __restrict__ v_a,
                                                float* __restrict__ scores) {
    __shared__ __align__(16) u16 Ash[BM * BK];   // swizzled: idx = r*64 + (k ^ ((r&7)<<3))
    __shared__ __align__(16) u16 Bsh[BN * BK];   // swizzled: idx = n*64 + (k ^ ((n&7)<<3))
    __shared__ float spl[8][64];

    const int tid = threadIdx.x;
    const int lane = tid & 63;
    const int wid = tid >> 6;           // 0..7
    const int lm = lane & 15;
    const int m0 = blockIdx.x * BM;
    const int b = m0 >> 11;             // T=2048 -> block fully inside one batch
    const int wmb = (wid >> 2) * 64;    // 0 or 64
    const int wnb = (wid & 3) * 128;    // 0,128,256,384
    const int kl = (lane >> 4) * 8;
    const int swz = (lane & 7) << 3;
    const int koff0 = kl ^ swz;
    const int koff1 = (kl + 32) ^ swz;

    // staging decomposition: thread -> (row sr, k-chunk sk)
    const int sr = tid >> 3;            // 0..63
    const int sk = (tid & 7) * 8;       // 0..56

    float sp[4][4];
#pragma unroll
    for (int i = 0; i < 4; ++i)
#pragma unroll
        for (int j = 0; j < 4; ++j) sp[i][j] = 0.f;

#pragma unroll 1
    for (int nt = 0; nt < NT; ++nt) {
        // init acc with wsa bias (broadcast along rows)
        f32x4 acc[4][8];
        {
#pragma unroll
            for (int fn = 0; fn < 8; ++fn) {
                const int cg = nt * BN + wnb + fn * 16 + lm;
                const float w = wsa[(size_t)b * A_DIM + cg];
#pragma unroll
                for (int fm = 0; fm < 4; ++fm) {
                    acc[fm][fn][0] = w; acc[fm][fn][1] = w;
                    acc[fm][fn][2] = w; acc[fm][fn][3] = w;
                }
            }
        }

#pragma unroll 1
        for (int kt = 0; kt < KSTEPS; ++kt) {
            __syncthreads();   // protect previous compute's LDS reads
            // ---- stage A: h[m0 .. m0+127][kt*64 .. +63] f32 -> bf16 swizzled
#pragma unroll
            for (int p = 0; p < 2; ++p) {
                const int r = p * 64 + sr;
                const float* src = &h[(size_t)(m0 + r) * D_DIM + kt * 64 + sk];
                const float4 f0 = *(const float4*)(src);
                const float4 f1 = *(const float4*)(src + 4);
                int4 w;
                w.x = (int)cvt_pk_bf16(f0.x, f0.y);
                w.y = (int)cvt_pk_bf16(f0.z, f0.w);
                w.z = (int)cvt_pk_bf16(f1.x, f1.y);
                w.w = (int)cvt_pk_bf16(f1.z, f1.w);
                *(int4*)&Ash[r * 64 + (sk ^ ((r & 7) << 3))] = w;
            }
            // ---- stage B: Ut[nt*512+n][kt*64 .. +63] bf16 swizzled
#pragma unroll
            for (int p = 0; p < 8; ++p) {
                const int n = p * 64 + sr;
                const int4 w = *(const int4*)&Ut[(size_t)(nt * BN + n) * D_DIM + kt * 64 + sk];
                *(int4*)&Bsh[n * 64 + (sk ^ ((n & 7) << 3))] = w;
            }
            __syncthreads();
            // ---- compute: 2 k-subtiles of 32
#pragma unroll
            for (int ks = 0; ks < 2; ++ks) {
                const int ko = ks ? koff1 : koff0;
                short8 af[4];
#pragma unroll
                for (int fm = 0; fm < 4; ++fm)
                    af[fm] = *(const short8*)&Ash[(wmb + fm * 16 + lm) * 64 + ko];
#pragma unroll
                for (int fn = 0; fn < 8; ++fn) {
                    const short8 bf = *(const short8*)&Bsh[(wnb + fn * 16 + lm) * 64 + ko];
#pragma unroll
                    for (int fm = 0; fm < 4; ++fm)
                        acc[fm][fn] = __builtin_amdgcn_mfma_f32_16x16x32_bf16(
                            af[fm], bf, acc[fm][fn], 0, 0, 0);
                }
            }
        }

        // ---- epilogue for this N-pass: sp += v[col] * tanh(acc)
#pragma unroll
        for (int fn = 0; fn < 8; ++fn) {
            const float vv = v_a[nt * BN + wnb + fn * 16 + lm];
#pragma unroll
            for (int fm = 0; fm < 4; ++fm)
#pragma unroll
                for (int r = 0; r < 4; ++r)
                    sp[fm][r] = fmaf(vv, fast_tanh(acc[fm][fn][r]), sp[fm][r]);
        }
    }

    // ---- reduce sp over the 16 column-lanes (same lane>>4 group)
#pragma unroll
    for (int fm = 0; fm < 4; ++fm)
#pragma unroll
        for (int r = 0; r < 4; ++r) {
            float v = sp[fm][r];
            v += __shfl_xor(v, 1);
            v += __shfl_xor(v, 2);
            v += __shfl_xor(v, 4);
            v += __shfl_xor(v, 8);
            sp[fm][r] = v;
        }
    if (lm == 0) {
#pragma unroll
        for (int fm = 0; fm < 4; ++fm)
#pragma unroll
            for (int r = 0; r < 4; ++r)
                spl[wid][fm * 16 + (lane >> 4) * 4 + r] = sp[fm][r];
    }
    __syncthreads();
    if (tid < BM) {
        const int row = tid;
        const int g = (row >> 6) * 4;
        const int ri = row & 63;
        const float s = spl[g + 0][ri] + spl[g + 1][ri] + spl[g + 2][ri] + spl[g + 3][ri];
        scores[m0 + row] = s;
    }
}

// ---------------- K2a: softmax over T (raw exp, as reference) ----------------
__global__ __launch_bounds__(256) void k_softmax(float* __restrict__ sc) {
    const int b = blockIdx.x;
    const int t = threadIdx.x;
    float e[8];
    float ssum = 0.f;
#pragma unroll
    for (int j = 0; j < 8; ++j) {
        e[j] = expf(sc[(size_t)b * T_DIM + j * 256 + t]);
        ssum += e[j];
    }
#pragma unroll
    for (int m = 1; m < 64; m <<= 1) ssum += __shfl_xor(ssum, m);
    __shared__ float wsum[4];
    if ((t & 63) == 0) wsum[t >> 6] = ssum;
    __syncthreads();
    const float S = wsum[0] + wsum[1] + wsum[2] + wsum[3];
    const float inv = 1.0f / S;
#pragma unroll
    for (int j = 0; j < 8; ++j)
        sc[(size_t)b * T_DIM + j * 256 + t] = e[j] * inv;
}

// ---------------- K2b: cpart[ts][b][d] = sum_{t in slice} a[b][t]*h[b][t][d] ----------------
#define TS_LEN (T_DIM / NSLICE)   // 128
__global__ __launch_bounds__(256) void k_ctx(const float* __restrict__ a,
                                             const float* __restrict__ h,
                                             float* __restrict__ cpart) {
    const int b = blockIdx.x;    // 0..31
    const int ts = blockIdx.y;   // 0..NSLICE-1
    const int d4 = threadIdx.x;  // d = d4*4
    float4 acc = {0.f, 0.f, 0.f, 0.f};
    const float* ab = a + (size_t)b * T_DIM + ts * TS_LEN;
    const float* hb = h + ((size_t)b * T_DIM + ts * TS_LEN) * D_DIM + d4 * 4;
#pragma unroll 4
    for (int i = 0; i < TS_LEN; ++i) {
        const float w = ab[i];
        const float4 v = *(const float4*)&hb[(size_t)i * D_DIM];
        acc.x = fmaf(w, v.x, acc.x);
        acc.y = fmaf(w, v.y, acc.y);
        acc.z = fmaf(w, v.z, acc.z);
        acc.w = fmaf(w, v.w, acc.w);
    }
    *(float4*)&cpart[((size_t)ts * B_DIM + b) * D_DIM + d4 * 4] = acc;
}

// ---------------- K2c: out = sum_ts cpart ----------------
__global__ __launch_bounds__(256) void k_csum(const float* __restrict__ cpart,
                                              float* __restrict__ out) {
    const int idx = blockIdx.x * 256 + threadIdx.x;  // 0..32767
    float s = 0.f;
#pragma unroll
    for (int ts = 0; ts < NSLICE; ++ts) s += cpart[(size_t)ts * 32768 + idx];
    out[idx] = s;
}

extern "C" void kernel_launch(void* const* d_in, const int* in_sizes, int n_in,
                              void* d_out, int out_size, void* d_ws, size_t ws_size,
                              hipStream_t stream) {
    const float* s   = (const float*)d_in[0];
    const float* h   = (const float*)d_in[1];
    const float* W_a = (const float*)d_in[2];
    const float* U_a = (const float*)d_in[3];
    const float* v_a = (const float*)d_in[4];
    float* out = (float*)d_out;

    if (ws_size < (size_t)WS_NEEDED) return;  // visible failure if ws too small

    float* wsf    = (float*)d_ws;
    float* scores = wsf;               // 65536
    float* wsa    = wsf + 65536;       // 32768
    float* cpart  = wsf + 98304;       // NSLICE*32768
    u16*   Ut     = (u16*)((char*)d_ws + 2490368);  // 1024*1024 bf16

    k_transpose_U<<<dim3(16, 16), 256, 0, stream>>>(U_a, Ut);
    k_ws<<<dim3(4, 32), 256, 0, stream>>>(s, W_a, wsa);
    k_scores<<<M_TOT / BM, 512, 0, stream>>>(h, Ut, wsa, v_a, scores);
    k_softmax<<<B_DIM, 256, 0, stream>>>(scores);
    k_ctx<<<dim3(B_DIM, NSLICE), 256, 0, stream>>>(scores, h, cpart);
    k_csum<<<128, 256, 0, stream>>>(cpart, out);
}